// Round 9
// baseline (291.834 us; speedup 1.0000x reference)
//
#include <hip/hip_runtime.h>

// PillarMaxPooling: Linear(10->64,nobias) -> BN1d(eval,eps=1e-3) -> ReLU ->
// segment_max -> clamp0.
//
// R1: 128M global atomicMax -> atomic-count bound (322 us).
// R2: per-point global scatter -> 4.4 GB cross-XCD RFO ping-pong.
// R5-R7: counting-sort + MFMA pool; R8: 512-thr pool (82 us) but sort-side
//     machinery (hist/scan/padfill/split, 5 launches) still ~180 us.
// R9: fixed-capacity region-keyed buckets (CAP=256 per (region,bucket);
//     mean 160, +7.6 sigma) eliminate hist/scan/padfill entirely. Split =
//     int4 idx load + one L2-local atomicAdd + 4B token store. Pool reads
//     cnt[] directly; never reads unwritten (poisoned) slots. Overflow
//     (adversarial inputs only) spills to a list handled by k_fix via
//     global atomicMax after pool.

#define C_IN   10
#define C_OUT  64
#define BSHIFT 7
#define BPILL  128
#define NREG   8
#define CAP    256
#define PBLK   512
#define SENT   (128u << 24)
#define OVFCAP 8192

typedef _Float16 half8 __attribute__((ext_vector_type(8)));
typedef float    f32x4 __attribute__((ext_vector_type(4)));

// ---------- K1: split — direct region-keyed token scatter ----------
__global__ __launch_bounds__(256)
void k_split(const int* __restrict__ idx, int* __restrict__ cnt,
             int* __restrict__ ovfn, int* __restrict__ ovf,
             unsigned int* __restrict__ sorted, int P, int NB) {
    const int gid = blockIdx.x * 256 + threadIdx.x;
    const int reg = blockIdx.x & (NREG - 1);
    const int p0 = gid * 4;
    if (p0 >= P) return;
    int4 m4;
    if (p0 + 3 < P) {
        m4 = ((const int4*)idx)[gid];
    } else {
        m4.x = idx[p0];
        m4.y = (p0 + 1 < P) ? idx[p0 + 1] : -1;
        m4.z = (p0 + 2 < P) ? idx[p0 + 2] : -1;
        m4.w = (p0 + 3 < P) ? idx[p0 + 3] : -1;
    }
    const int mv[4] = {m4.x, m4.y, m4.z, m4.w};
#pragma unroll
    for (int j = 0; j < 4; ++j) {
        int m = mv[j];
        if (m < 0) continue;
        int p = p0 + j;
        int e = reg * NB + (m >> BSHIFT);
        int s = atomicAdd(&cnt[e], 1);
        if (s < CAP) {
            sorted[(size_t)e * CAP + s] =
                (unsigned)p | ((unsigned)(m & (BPILL - 1)) << 24);
        } else {
            int ai = atomicAdd(ovfn, 1);
            if (ai < OVFCAP) { ovf[2 * ai] = p; ovf[2 * ai + 1] = m; }
        }
    }
}

// ---------- K2: pool — lane-per-point gather, MFMA, LDS atomicMax ----------
__global__ __launch_bounds__(PBLK, 8)
void k_pool(const float* __restrict__ gf,
            const unsigned int* __restrict__ sorted,
            const int* __restrict__ cnt,
            const float* __restrict__ W,
            const float* __restrict__ gamma,
            const float* __restrict__ beta,
            const float* __restrict__ rmean,
            const float* __restrict__ rvar,
            float* __restrict__ out, int M, int NB) {
    __shared__ unsigned int acc[129 * 65];   // stride 65; row 128 = trash (SENT)
    const int t = threadIdx.x;
    const int lane = t & 63;
    const int wv = t >> 6;                   // wave == region 0..7
    const int n = lane & 15;
    const int q = lane >> 4;

    for (int i = t; i < 129 * 65; i += PBLK) acc[i] = 0u;

    // B fragments: W rows k>=10 zeroed -> A K-padding free
    half8 bfrag[4];
    float inv[4], bia[4];
#pragma unroll
    for (int tt = 0; tt < 4; ++tt) {
        int c = tt * 16 + n;
#pragma unroll
        for (int j = 0; j < 8; ++j) {
            int k = q * 8 + j;
            bfrag[tt][j] = (k < C_IN) ? (_Float16)W[k * C_OUT + c] : (_Float16)0.f;
        }
        float is = gamma[c] * rsqrtf(rvar[c] + 1e-3f);
        inv[tt] = is;
        bia[tt] = fmaf(-rmean[c], is, beta[c]);
    }
    __syncthreads();

    const int e  = wv * NB + blockIdx.x;     // this wave's (region,bucket)
    const int s0 = e * CAP;
    const int s1 = s0 + min(cnt[e], CAP);    // only written slots are read
    const float2* gf2 = (const float2*)gf;

    for (int rb = s0; rb < s1; rb += 64) {
        // lane-per-point: full-wave 40B contiguous gather + packed cvt
        unsigned v = (rb + lane < s1) ? sorted[rb + lane] : SENT;
        const float2* src = gf2 + (size_t)(v & 0xFFFFFFu) * 5;
        float2 x0 = src[0], x1 = src[1], x2 = src[2], x3 = src[3], x4 = src[4];
        int u0 = __builtin_bit_cast(int, __builtin_amdgcn_cvt_pkrtz(x0.x, x0.y));
        int u1 = __builtin_bit_cast(int, __builtin_amdgcn_cvt_pkrtz(x1.x, x1.y));
        int u2 = __builtin_bit_cast(int, __builtin_amdgcn_cvt_pkrtz(x2.x, x2.y));
        int u3 = __builtin_bit_cast(int, __builtin_amdgcn_cvt_pkrtz(x3.x, x3.y));
        int u4 = __builtin_bit_cast(int, __builtin_amdgcn_cvt_pkrtz(x4.x, x4.y));

        const int ng = min(4, (s1 - rb + 15) >> 4);   // ceil: partial last group
#pragma unroll
        for (int g = 0; g < 4; ++g) {
            if (g >= ng) break;                  // wave-uniform
            const int sl = (g << 4) + n;         // source lane: point g*16+n
            int b0 = __shfl(u0, sl, 64);
            int b1 = __shfl(u1, sl, 64);
            int b2 = __shfl(u2, sl, 64);
            int b3 = __shfl(u3, sl, 64);
            int b4 = __shfl(u4, sl, 64);
            int4 a32;
            a32.x = (q == 0) ? b0 : ((q == 1) ? b4 : 0);
            a32.y = (q == 0) ? b1 : 0;
            a32.z = (q == 0) ? b2 : 0;
            a32.w = (q == 0) ? b3 : 0;
            half8 a = __builtin_bit_cast(half8, a32);
            f32x4 z = {0.f, 0.f, 0.f, 0.f};
            f32x4 d0 = __builtin_amdgcn_mfma_f32_16x16x32_f16(a, bfrag[0], z, 0, 0, 0);
            f32x4 d1 = __builtin_amdgcn_mfma_f32_16x16x32_f16(a, bfrag[1], z, 0, 0, 0);
            f32x4 d2 = __builtin_amdgcn_mfma_f32_16x16x32_f16(a, bfrag[2], z, 0, 0, 0);
            f32x4 d3 = __builtin_amdgcn_mfma_f32_16x16x32_f16(a, bfrag[3], z, 0, 0, 0);
#pragma unroll
            for (int r = 0; r < 4; ++r) {        // C row = 4q+r = point
                int pv = __shfl((int)v, (g << 4) + (q << 2) + r, 64);
                int abase = (int)(((unsigned)pv) >> 24) * 65 + n;   // ml row
                float h0 = fmaxf(fmaf(d0[r], inv[0], bia[0]), 0.f);
                float h1 = fmaxf(fmaf(d1[r], inv[1], bia[1]), 0.f);
                float h2 = fmaxf(fmaf(d2[r], inv[2], bia[2]), 0.f);
                float h3 = fmaxf(fmaf(d3[r], inv[3], bia[3]), 0.f);
                atomicMax(&acc[abase +  0], __float_as_uint(h0));
                atomicMax(&acc[abase + 16], __float_as_uint(h1));
                atomicMax(&acc[abase + 32], __float_as_uint(h2));
                atomicMax(&acc[abase + 48], __float_as_uint(h3));
            }
        }
    }
    __syncthreads();

    // coalesced writeback of 128 pillars x 64 channels
    const int mbase = blockIdx.x * BPILL;
#pragma unroll
    for (int i = 0; i < (BPILL * C_OUT) / PBLK; ++i) {
        int wdx = i * PBLK + t;
        int row = wdx >> 6, c = wdx & 63;
        int m = mbase + row;
        if (m < M) out[(size_t)m * C_OUT + c] = __uint_as_float(acc[row * 65 + c]);
    }
}

// ---------- K3: overflow fallback (normally 0 entries) ----------
__global__ __launch_bounds__(256)
void k_fix(const int* __restrict__ ovfn, const int* __restrict__ ovf,
           const float* __restrict__ gf,
           const float* __restrict__ W,
           const float* __restrict__ gamma,
           const float* __restrict__ beta,
           const float* __restrict__ rmean,
           const float* __restrict__ rvar,
           float* __restrict__ out) {
    const int nv = min(*ovfn, OVFCAP);
    if (nv == 0) return;
    const int lane = threadIdx.x & 63;
    const int wid = (blockIdx.x * 256 + threadIdx.x) >> 6;
    const int nw = gridDim.x * 4;
    float w[C_IN];
#pragma unroll
    for (int k = 0; k < C_IN; ++k) w[k] = W[k * C_OUT + lane];
    const float is = gamma[lane] * rsqrtf(rvar[lane] + 1e-3f);
    const float bi = fmaf(-rmean[lane], is, beta[lane]);
    for (int i = wid; i < nv; i += nw) {
        int p = ovf[2 * i], m = ovf[2 * i + 1];
        float y = 0.f;
#pragma unroll
        for (int k = 0; k < C_IN; ++k) y = fmaf(gf[(size_t)p * C_IN + k], w[k], y);
        float h = fmaxf(fmaf(y, is, bi), 0.f);
        atomicMax((unsigned int*)(out + (size_t)m * C_OUT + lane),
                  __float_as_uint(h));
    }
}

extern "C" void kernel_launch(void* const* d_in, const int* in_sizes, int n_in,
                              void* d_out, int out_size, void* d_ws, size_t ws_size,
                              hipStream_t stream) {
    const float* gf    = (const float*)d_in[0];
    const int*   idx   = (const int*)  d_in[1];
    const float* W     = (const float*)d_in[3];
    const float* gamma = (const float*)d_in[4];
    const float* beta  = (const float*)d_in[5];
    const float* rmean = (const float*)d_in[6];
    const float* rvar  = (const float*)d_in[7];
    float*       out   = (float*)d_out;

    const int P  = in_sizes[0] / C_IN;
    const int M  = out_size / C_OUT;
    const int NB = (M + BPILL - 1) >> BSHIFT;     // 1563 for M=200k
    const int E  = NREG * NB;                     // 12504

    char* ws = (char*)d_ws;
    auto align256 = [](size_t x) { return (x + 255) & ~(size_t)255; };
    int* cnt  = (int*)ws;  ws += align256((size_t)(E + 1) * 4);  // cnt[E] + ovfn
    int* ovfn = cnt + E;
    int* ovf  = (int*)ws;  ws += align256((size_t)OVFCAP * 8);
    unsigned int* sorted = (unsigned int*)ws;     // E*CAP u32 (~12.8 MB)

    hipMemsetAsync(cnt, 0, (size_t)(E + 1) * 4, stream);
    k_split<<<(P + 1023) / 1024, 256, 0, stream>>>(idx, cnt, ovfn, ovf, sorted, P, NB);
    k_pool <<<NB, PBLK, 0, stream>>>(gf, sorted, cnt, W, gamma, beta,
                                     rmean, rvar, out, M, NB);
    k_fix  <<<16, 256, 0, stream>>>(ovfn, ovf, gf, W, gamma, beta,
                                    rmean, rvar, out);
}